// Round 14
// baseline (147.691 us; speedup 1.0000x reference)
//
#include <hip/hip_runtime.h>
#include <hip/hip_bf16.h>
#include <math.h>

#define L_SEQ 1024
#define BSZ 8
#define EMB 512
#define NH 8
#define DQ 64
#define BH 64          // BSZ*NH
#define NQKV 1536      // 3*NH*DQ

// Q is pre-scaled by (emb_dim/n_head)^-0.5 * log2(e) so that
// softmax numerator = exp2(mfma_score) with zero extra VALU per element.
#define SCALE_Q 0.18033688f

typedef __attribute__((ext_vector_type(8))) short short8;   // 8 bf16 = 4 VGPR
typedef __attribute__((ext_vector_type(4))) float f32x4;

__device__ __forceinline__ unsigned short bf16u(float x) {
  __hip_bfloat16 h = __float2bfloat16(x);
  return *(unsigned short*)&h;
}

__device__ __forceinline__ short8 pack_bf16x8(float4 a, float4 b) {
  short8 o;
  o[0] = bf16u(a.x); o[1] = bf16u(a.y); o[2] = bf16u(a.z); o[3] = bf16u(a.w);
  o[4] = bf16u(b.x); o[5] = bf16u(b.y); o[6] = bf16u(b.z); o[7] = bf16u(b.w);
  return o;
}

// ---------------------------------------------------------------------------
// Kernel A (fused convert + GEMM): QKV projection, bf16 MFMA, reads f32
// emb/W DIRECTLY (to_bf16 kernel eliminated). K-loop: register prefetch of
// f32 (post-barrier), in-register f32->bf16 convert, ds_write, dbuf, ONE
// barrier per iter (replaces the m97 2-barrier global_load_lds pattern whose
// vmcnt(0) drain dominates at only 16 iters). Staging LDS (32 KB) aliased
// with the 33 KB Cs epilogue tile. Q gets SCALE_Q folded in.
// Block (0,0) zero-inits Oacc/cnt for attn_fused (kernel-boundary visible).
// ---------------------------------------------------------------------------
__global__ __launch_bounds__(256) void qkv_mfma(
    const float* __restrict__ A,    // emb f32 [8192][512]
    const float* __restrict__ B,    // W   f32 [1536][512]
    const float* __restrict__ bias,
    unsigned short* __restrict__ Qb, unsigned short* __restrict__ Kb,
    unsigned short* __restrict__ Vb,
    float* __restrict__ Oacc, int* __restrict__ cnt) {
  __shared__ __align__(16) unsigned short smem[128 * 132];  // 33792 B
  // staging views (first 32 KB): As[2][128][32], Bs[2][128][32]
  unsigned short (*As)[128][32] = (unsigned short(*)[128][32])smem;
  unsigned short (*Bs)[128][32] = (unsigned short(*)[128][32])(smem + 8192);
  unsigned short (*Cs)[132] = (unsigned short(*)[132])smem;  // epilogue alias

  const int tid = threadIdx.x;
  const int wave = tid >> 6, lane = tid & 63;
  const int quad = lane >> 4, col = lane & 15;
  const int wr = wave >> 1, wc = wave & 1;
  const int m0 = blockIdx.y * 128, n0 = blockIdx.x * 128;

  if (blockIdx.x == 0 && blockIdx.y == 0) {
    for (int i = tid; i < BH * 64; i += 256) Oacc[i] = 0.f;
    if (tid < BH) cnt[tid] = 0;
  }

  // staging: thread handles row = tid>>1 (0..127), half = tid&1 (16 shorts)
  const int srow = tid >> 1, koff = (tid & 1) * 16;
  const float* Ag = A + (size_t)(m0 + srow) * EMB + koff;
  const float* Bg = B + (size_t)(n0 + srow) * EMB + koff;

  f32x4 acc[4][4] = {};
  float4 a0, a1, a2, a3, b0, b1, b2, b3;

  // prefetch tile 0
  a0 = *(const float4*)&Ag[0];  a1 = *(const float4*)&Ag[4];
  a2 = *(const float4*)&Ag[8];  a3 = *(const float4*)&Ag[12];
  b0 = *(const float4*)&Bg[0];  b1 = *(const float4*)&Bg[4];
  b2 = *(const float4*)&Bg[8];  b3 = *(const float4*)&Bg[12];

#pragma unroll 2
  for (int kt = 0; kt < 16; ++kt) {
    const int buf = kt & 1;
    *(short8*)&As[buf][srow][koff] = pack_bf16x8(a0, a1);
    *(short8*)&As[buf][srow][koff + 8] = pack_bf16x8(a2, a3);
    *(short8*)&Bs[buf][srow][koff] = pack_bf16x8(b0, b1);
    *(short8*)&Bs[buf][srow][koff + 8] = pack_bf16x8(b2, b3);
    __syncthreads();
    if (kt + 1 < 16) {  // post-barrier prefetch: in flight through compute
      const float* Ap = Ag + (kt + 1) * 32;
      const float* Bp = Bg + (kt + 1) * 32;
      a0 = *(const float4*)&Ap[0];  a1 = *(const float4*)&Ap[4];
      a2 = *(const float4*)&Ap[8];  a3 = *(const float4*)&Ap[12];
      b0 = *(const float4*)&Bp[0];  b1 = *(const float4*)&Bp[4];
      b2 = *(const float4*)&Bp[8];  b3 = *(const float4*)&Bp[12];
    }
    short8 af[4], bf[4];
#pragma unroll
    for (int i = 0; i < 4; ++i)
      af[i] = *(const short8*)&As[buf][wr * 64 + i * 16 + col][quad * 8];
#pragma unroll
    for (int j = 0; j < 4; ++j)
      bf[j] = *(const short8*)&Bs[buf][wc * 64 + j * 16 + col][quad * 8];
#pragma unroll
    for (int i = 0; i < 4; ++i)
#pragma unroll
      for (int j = 0; j < 4; ++j)
        acc[i][j] =
            __builtin_amdgcn_mfma_f32_16x16x32_bf16(af[i], bf[j], acc[i][j],
                                                    0, 0, 0);
  }

  __syncthreads();  // all staging reads done before Cs alias overwrite
#pragma unroll
  for (int j = 0; j < 4; ++j) {
    const int n = wc * 64 + j * 16 + col;     // tile col 0..127
    const float bj = bias[n0 + n];
    const bool isQ = (((n0 + n) >> 6) % 3) == 0;
#pragma unroll
    for (int i = 0; i < 4; ++i) {
      const int mrow = wr * 64 + i * 16 + quad * 4;
#pragma unroll
      for (int r = 0; r < 4; ++r) {
        float val = acc[i][j][r] + bj;
        if (isQ) val *= SCALE_Q;
        Cs[mrow + r][n] = bf16u(val);
      }
    }
  }
  __syncthreads();
  const int bb = lane >> 3, oct = lane & 7;
#pragma unroll
  for (int e = 0; e < 8; ++e) {
    const int idx = wave * 8 + e;
    const int half = idx >> 4, l = idx & 15;
    const int G = (n0 >> 6) + half;       // 64-col block id, 0..23
    const int h = G / 3, sel = G % 3;
    unsigned short* dst = (sel == 0) ? Qb : (sel == 1) ? Kb : Vb;
    short8 v = *(const short8*)&Cs[l * 8 + bb][half * 64 + oct * 8];
    const int lglob = (m0 >> 3) + l;
    *(short8*)&dst[(((size_t)(bb * NH + h)) * L_SEQ + lglob) * DQ + oct * 8] = v;
  }
}

// ---------------------------------------------------------------------------
// Kernel B (fused attention, v3): 512 thr (R12's best shape, 16 waves/CU),
// grid 512 = (bh=blk&63 -> XCD-local, qc=blk>>6 in 0..7), block owns 128
// q-rows, wave owns 16. 128-KEY staging tiles: barriers halve vs R12
// (8 iters/pass instead of 16), same traffic, same frag reads. Dbuf +
// post-barrier prefetch. PASS 1 -> invz[4] in regs; PASS 2 -> cs colsums;
// wave-reduce; V-combine; atomicAdd Oacc; 8th block per bh does GroupNorm.
// ---------------------------------------------------------------------------
__global__ __launch_bounds__(512) void attn_fused(
    const unsigned short* __restrict__ Qb, const unsigned short* __restrict__ Kb,
    const unsigned short* __restrict__ Vb,
    const float* __restrict__ gnw, const float* __restrict__ gnb,
    float* __restrict__ Oacc, int* __restrict__ cnt, float* __restrict__ out) {
  const int bh = blockIdx.x & 63;   // blk%8 = bh%8 -> same-bh blocks same XCD
  const int qc = blockIdx.x >> 6;   // 0..7, 128 q-rows each
  const int tid = threadIdx.x;
  const int wave = tid >> 6, lane = tid & 63;
  const int quad = lane >> 4, col = lane & 15;

  __shared__ __align__(16) unsigned short Ks[2][128][72];  // 36.9 KB
  __shared__ float cs[8][1024];                            // 32 KB
  __shared__ int lastFlag;

  const unsigned short* kbase = &Kb[(size_t)bh * L_SEQ * DQ];

  // Q fragments for this wave's 16 rows (both passes)
  const unsigned short* qp =
      &Qb[((size_t)bh * L_SEQ + qc * 128 + wave * 16 + col) * DQ];
  short8 qa0 = *(const short8*)&qp[quad * 8];
  short8 qa1 = *(const short8*)&qp[32 + quad * 8];

  const int sr = tid >> 2;         // staging row 0..127
  const int so = (tid & 3) * 16;   // staging col offset (shorts)

  // ---------------- PASS 1: Z for own 16 rows ----------------
  float zacc[4] = {0.f, 0.f, 0.f, 0.f};
  short8 st0, st1;
  {
    const unsigned short* s8 = kbase + (size_t)sr * DQ + so;
    st0 = *(const short8*)s8;
    st1 = *(const short8*)(s8 + 8);
  }

#pragma unroll 2
  for (int kt = 0; kt < 8; ++kt) {
    const int buf = kt & 1;
    *(short8*)&Ks[buf][sr][so] = st0;
    *(short8*)&Ks[buf][sr][so + 8] = st1;
    __syncthreads();
    if (kt + 1 < 8) {  // post-barrier prefetch: in flight through compute
      const unsigned short* s8 =
          kbase + ((size_t)((kt + 1) * 128 + sr)) * DQ + so;
      st0 = *(const short8*)s8;
      st1 = *(const short8*)(s8 + 8);
    }
#pragma unroll
    for (int sub = 0; sub < 8; ++sub) {
      const unsigned short* kp = &Ks[buf][sub * 16 + col][0];
      short8 kb0 = *(const short8*)&kp[quad * 8];
      short8 kb1 = *(const short8*)&kp[32 + quad * 8];
      f32x4 s = {0.f, 0.f, 0.f, 0.f};
      s = __builtin_amdgcn_mfma_f32_16x16x32_bf16(qa0, kb0, s, 0, 0, 0);
      s = __builtin_amdgcn_mfma_f32_16x16x32_bf16(qa1, kb1, s, 0, 0, 0);
#pragma unroll
      for (int j = 0; j < 4; ++j) zacc[j] += __builtin_amdgcn_exp2f(s[j]);
    }
  }
  float invz[4];
#pragma unroll
  for (int j = 0; j < 4; ++j) {
    float z = zacc[j];
#pragma unroll
    for (int off = 1; off <= 8; off <<= 1) z += __shfl_xor(z, off, 64);
    invz[j] = __builtin_amdgcn_rcpf(z);   // replicated across the quad
  }

  // ---------------- PASS 2: colsum contributions (K is L2-hot) ----------
  {
    const unsigned short* s8 = kbase + (size_t)sr * DQ + so;
    st0 = *(const short8*)s8;
    st1 = *(const short8*)(s8 + 8);
  }
#pragma unroll 2
  for (int kt = 0; kt < 8; ++kt) {
    const int buf = kt & 1;
    *(short8*)&Ks[buf][sr][so] = st0;
    *(short8*)&Ks[buf][sr][so + 8] = st1;
    __syncthreads();
    if (kt + 1 < 8) {
      const unsigned short* s8 =
          kbase + ((size_t)((kt + 1) * 128 + sr)) * DQ + so;
      st0 = *(const short8*)s8;
      st1 = *(const short8*)(s8 + 8);
    }
#pragma unroll
    for (int sub = 0; sub < 8; ++sub) {
      const unsigned short* kp = &Ks[buf][sub * 16 + col][0];
      short8 kb0 = *(const short8*)&kp[quad * 8];
      short8 kb1 = *(const short8*)&kp[32 + quad * 8];
      f32x4 s = {0.f, 0.f, 0.f, 0.f};
      s = __builtin_amdgcn_mfma_f32_16x16x32_bf16(qa0, kb0, s, 0, 0, 0);
      s = __builtin_amdgcn_mfma_f32_16x16x32_bf16(qa1, kb1, s, 0, 0, 0);
      float partial = 0.f;
#pragma unroll
      for (int j = 0; j < 4; ++j)
        partial = fmaf(__builtin_amdgcn_exp2f(s[j]), invz[j], partial);
      // sum over the 4 quads (this wave's 16 rows); key = kt*128+sub*16+col
      partial += __shfl_xor(partial, 16, 64);
      partial += __shfl_xor(partial, 32, 64);
      if (quad == 0) cs[wave][kt * 128 + sub * 16 + col] = partial;
    }
  }
  __syncthreads();
  // reduce cs over the 8 waves -> cs[0][m]
  for (int m = tid; m < 1024; m += 512) {
    float a = cs[0][m] + cs[1][m] + cs[2][m] + cs[3][m] +
              cs[4][m] + cs[5][m] + cs[6][m] + cs[7][m];
    cs[0][m] = a;
  }
  __syncthreads();

  // V-combine: partial O[d] = sum over ALL 1024 keys of cs[0][m]*V[m][d]
  const int d = tid & 63, g8 = tid >> 6;   // 8 groups x 128 keys
  {
    const unsigned short* vb = &Vb[((size_t)bh * L_SEQ + g8 * 128) * DQ + d];
    float oacc = 0.f;
#pragma unroll 8
    for (int mm = 0; mm < 128; ++mm) {
      __hip_bfloat16 v;
      *(unsigned short*)&v = vb[(size_t)mm * DQ];
      oacc = fmaf(cs[0][g8 * 128 + mm], __bfloat162float(v), oacc);
    }
    cs[1][g8 * 64 + d] = oacc;   // cs[1] rows free after reduce
  }
  __syncthreads();
  if (tid < 64) {
    float p = 0.f;
#pragma unroll
    for (int g = 0; g < 8; ++g) p += cs[1][g * 64 + tid];
    atomicAdd(&Oacc[(size_t)bh * 64 + tid], p);
  }
  if (tid == 0) {
    __threadfence();                      // release: O adds visible first
    lastFlag = (atomicAdd(&cnt[bh], 1) == 7);
  }
  __syncthreads();
  if (lastFlag && tid < 64) {
    __threadfence();                      // acquire
    float v = atomicAdd(&Oacc[(size_t)bh * 64 + tid], 0.f);
    float s = v;
#pragma unroll
    for (int off = 32; off >= 1; off >>= 1) s += __shfl_xor(s, off, 64);
    float mean = s * (1.f / 64.f);
    float diff = v - mean;
    float sq = diff * diff;
#pragma unroll
    for (int off = 32; off >= 1; off >>= 1) sq += __shfl_xor(sq, off, 64);
    float var = sq * (1.f / 64.f);
    float o = diff * rsqrtf(var + 1e-5f);
    const int b = bh >> 3, h = bh & 7;
    out[(size_t)b * 512 + h * 64 + tid] = o * gnw[h] + gnb[h];
  }
}

extern "C" void kernel_launch(void* const* d_in, const int* in_sizes, int n_in,
                              void* d_out, int out_size, void* d_ws,
                              size_t ws_size, hipStream_t stream) {
  (void)in_sizes; (void)n_in; (void)out_size; (void)ws_size;
  const float* emb  = (const float*)d_in[0];
  const float* W    = (const float*)d_in[1];
  const float* bias = (const float*)d_in[2];
  const float* gnw  = (const float*)d_in[3];
  const float* gnb  = (const float*)d_in[4];
  float* out = (float*)d_out;

  char* ws = (char*)d_ws;
  const size_t perQ = (size_t)BH * L_SEQ * DQ;        // 4,194,304 elems
  unsigned short* Qb = (unsigned short*)ws;           // 8 MB
  unsigned short* Kb = Qb + perQ;                     // 8 MB
  unsigned short* Vb = Kb + perQ;                     // 8 MB
  float* Oacc = (float*)(ws + 32u * 1024 * 1024);     // 16 KB
  int*   cnt  = (int*)(ws + 32u * 1024 * 1024 + 64u * 1024);

  qkv_mfma<<<dim3(NQKV / 128, 8192 / 128), 256, 0, stream>>>(
      emb, W, bias, Qb, Kb, Vb, Oacc, cnt);
  attn_fused<<<dim3(512), 512, 0, stream>>>(Qb, Kb, Vb, gnw, gnb,
                                            Oacc, cnt, out);
}

// Round 15
// 142.006 us; speedup vs baseline: 1.0400x; 1.0400x over previous
//
#include <hip/hip_runtime.h>
#include <hip/hip_bf16.h>
#include <math.h>

#define L_SEQ 1024
#define BSZ 8
#define EMB 512
#define NH 8
#define DQ 64
#define BH 64          // BSZ*NH
#define NQKV 1536      // 3*NH*DQ

// Q is pre-scaled by (emb_dim/n_head)^-0.5 * log2(e) so that
// softmax numerator = exp2(mfma_score) with zero extra VALU per element.
#define SCALE_Q 0.18033688f

typedef __attribute__((ext_vector_type(8))) short short8;    // 8 bf16
typedef __attribute__((ext_vector_type(4))) float f32x4;
typedef __attribute__((ext_vector_type(16))) float f32x16;   // 32x32 acc

__device__ __forceinline__ unsigned short bf16u(float x) {
  __hip_bfloat16 h = __float2bfloat16(x);
  return *(unsigned short*)&h;
}

__device__ __forceinline__ short8 pack_bf16x8(float4 a, float4 b) {
  short8 o;
  o[0] = bf16u(a.x); o[1] = bf16u(a.y); o[2] = bf16u(a.z); o[3] = bf16u(a.w);
  o[4] = bf16u(b.x); o[5] = bf16u(b.y); o[6] = bf16u(b.z); o[7] = bf16u(b.w);
  return o;
}

// ---------------------------------------------------------------------------
// Kernel A (fused convert + GEMM): QKV projection, bf16 MFMA, f32 inputs.
// v2: 1-D grid 768 with XCD-aware swizzle — XCD x owns an 8-m-tile x 12-n
// stripe (A 2MB + B 3MB ~= one XCD L2), cutting redundant f32 re-fetch
// (R14: 72MB HBM, A read ~12x / B ~64x across XCDs). Rest unchanged.
// ---------------------------------------------------------------------------
__global__ __launch_bounds__(256) void qkv_mfma(
    const float* __restrict__ A,    // emb f32 [8192][512]
    const float* __restrict__ B,    // W   f32 [1536][512]
    const float* __restrict__ bias,
    unsigned short* __restrict__ Qb, unsigned short* __restrict__ Kb,
    unsigned short* __restrict__ Vb,
    float* __restrict__ Oacc, int* __restrict__ cnt) {
  __shared__ __align__(16) unsigned short smem[128 * 132];  // 33792 B
  unsigned short (*As)[128][32] = (unsigned short(*)[128][32])smem;
  unsigned short (*Bs)[128][32] = (unsigned short(*)[128][32])(smem + 8192);
  unsigned short (*Cs)[132] = (unsigned short(*)[132])smem;  // epilogue alias

  const int tid = threadIdx.x;
  const int wave = tid >> 6, lane = tid & 63;
  const int quad = lane >> 4, col = lane & 15;
  const int wr = wave >> 1, wc = wave & 1;
  // XCD-aware tile assignment: xcd = blk&7 (dispatch round-robin), each XCD
  // covers m-tiles xcd*8..+7 x all 12 n-tiles.
  const int blk = blockIdx.x;
  const int xcd = blk & 7, idx = blk >> 3;      // idx 0..95
  const int m0 = (xcd * 8 + idx / 12) * 128;
  const int n0 = (idx % 12) * 128;

  if (blk == 0) {
    for (int i = tid; i < BH * 64; i += 256) Oacc[i] = 0.f;
    if (tid < BH) cnt[tid] = 0;
  }

  const int srow = tid >> 1, koff = (tid & 1) * 16;
  const float* Ag = A + (size_t)(m0 + srow) * EMB + koff;
  const float* Bg = B + (size_t)(n0 + srow) * EMB + koff;

  f32x4 acc[4][4] = {};
  float4 a0, a1, a2, a3, b0, b1, b2, b3;

  a0 = *(const float4*)&Ag[0];  a1 = *(const float4*)&Ag[4];
  a2 = *(const float4*)&Ag[8];  a3 = *(const float4*)&Ag[12];
  b0 = *(const float4*)&Bg[0];  b1 = *(const float4*)&Bg[4];
  b2 = *(const float4*)&Bg[8];  b3 = *(const float4*)&Bg[12];

#pragma unroll 2
  for (int kt = 0; kt < 16; ++kt) {
    const int buf = kt & 1;
    *(short8*)&As[buf][srow][koff] = pack_bf16x8(a0, a1);
    *(short8*)&As[buf][srow][koff + 8] = pack_bf16x8(a2, a3);
    *(short8*)&Bs[buf][srow][koff] = pack_bf16x8(b0, b1);
    *(short8*)&Bs[buf][srow][koff + 8] = pack_bf16x8(b2, b3);
    __syncthreads();
    if (kt + 1 < 16) {
      const float* Ap = Ag + (kt + 1) * 32;
      const float* Bp = Bg + (kt + 1) * 32;
      a0 = *(const float4*)&Ap[0];  a1 = *(const float4*)&Ap[4];
      a2 = *(const float4*)&Ap[8];  a3 = *(const float4*)&Ap[12];
      b0 = *(const float4*)&Bp[0];  b1 = *(const float4*)&Bp[4];
      b2 = *(const float4*)&Bp[8];  b3 = *(const float4*)&Bp[12];
    }
    short8 af[4], bf[4];
#pragma unroll
    for (int i = 0; i < 4; ++i)
      af[i] = *(const short8*)&As[buf][wr * 64 + i * 16 + col][quad * 8];
#pragma unroll
    for (int j = 0; j < 4; ++j)
      bf[j] = *(const short8*)&Bs[buf][wc * 64 + j * 16 + col][quad * 8];
#pragma unroll
    for (int i = 0; i < 4; ++i)
#pragma unroll
      for (int j = 0; j < 4; ++j)
        acc[i][j] =
            __builtin_amdgcn_mfma_f32_16x16x32_bf16(af[i], bf[j], acc[i][j],
                                                    0, 0, 0);
  }

  __syncthreads();  // staging reads done before Cs alias overwrite
#pragma unroll
  for (int j = 0; j < 4; ++j) {
    const int n = wc * 64 + j * 16 + col;
    const float bj = bias[n0 + n];
    const bool isQ = (((n0 + n) >> 6) % 3) == 0;
#pragma unroll
    for (int i = 0; i < 4; ++i) {
      const int mrow = wr * 64 + i * 16 + quad * 4;
#pragma unroll
      for (int r = 0; r < 4; ++r) {
        float val = acc[i][j][r] + bj;
        if (isQ) val *= SCALE_Q;
        Cs[mrow + r][n] = bf16u(val);
      }
    }
  }
  __syncthreads();
  const int bb = lane >> 3, oct = lane & 7;
#pragma unroll
  for (int e = 0; e < 8; ++e) {
    const int idx2 = wave * 8 + e;
    const int half = idx2 >> 4, l = idx2 & 15;
    const int G = (n0 >> 6) + half;
    const int h = G / 3, sel = G % 3;
    unsigned short* dst = (sel == 0) ? Qb : (sel == 1) ? Kb : Vb;
    short8 v = *(const short8*)&Cs[l * 8 + bb][half * 64 + oct * 8];
    const int lglob = (m0 >> 3) + l;
    *(short8*)&dst[(((size_t)(bb * NH + h)) * L_SEQ + lglob) * DQ + oct * 8] = v;
  }
}

// ---------------------------------------------------------------------------
// Kernel B (fused attention, v4 — 32x32 MFMA + key-split):
// 512 thr, grid 512 = (bh=blk&63 XCD-local, qc=blk>>6), block owns 128 rows.
// Wave w: rowset rs=w>>1 (32 rows via mfma_32x32x16 A-operand m=lane&31),
// key-half h=w&1 (512 keys). One MFMA covers 32 rows -> LDS B-frag reads
// halve vs 16x16, and 16 independent exp2 per MFMA (4x ILP; R12-R14 showed
// the kernel is dependency-latency bound, not pipe bound).
// Per round: stage TWO 64-key tiles (one per half), dbuf, post-barrier
// prefetch, 8 rounds/pass. Z exchanged between half-waves via LDS.
// A-layout assumed m=lane&31, k=(lane>>5)*8+j (extrapolated from verified
// 16x16). C/D: col=lane&31, row=(reg&3)+8*(reg>>2)+4*(lane>>5) (m74/m101).
// ---------------------------------------------------------------------------
__global__ __launch_bounds__(512) void attn_fused(
    const unsigned short* __restrict__ Qb, const unsigned short* __restrict__ Kb,
    const unsigned short* __restrict__ Vb,
    const float* __restrict__ gnw, const float* __restrict__ gnb,
    float* __restrict__ Oacc, int* __restrict__ cnt, float* __restrict__ out) {
  const int bh = blockIdx.x & 63;
  const int qc = blockIdx.x >> 6;   // 0..7, 128 q-rows each
  const int tid = threadIdx.x;
  const int wave = tid >> 6, lane = tid & 63;
  const int rs = wave >> 1, h = wave & 1;
  const int kcol = lane & 31, lh = lane >> 5;

  __shared__ __align__(16) unsigned short Ks[2][2][64][72];  // [dbuf][half] 36.9KB
  __shared__ float cs[8][512];   // 16 KB (cs[0][0..255] doubles as Zp)
  __shared__ float red[8][64];   // 2 KB
  __shared__ int lastFlag;
  float* zp = (float*)cs;        // zp[h*128 + rowInBlock], 256 floats

  const unsigned short* kbase = &Kb[(size_t)bh * L_SEQ * DQ];

  // Q fragments: rows qc*128 + rs*32 + kcol; k = ks*16 + lh*8 (4 ksteps)
  short8 qA[4];
  {
    const unsigned short* qp =
        &Qb[((size_t)bh * L_SEQ + qc * 128 + rs * 32 + kcol) * DQ];
#pragma unroll
    for (int ks = 0; ks < 4; ++ks) qA[ks] = *(const short8*)&qp[ks * 16 + lh * 8];
  }

  // staging: thread -> (tile-half th, row sr, 32B chunk so)
  const int th = tid >> 8, sr = (tid >> 2) & 63, so = (tid & 3) * 16;

  // ---------------- PASS 1: Z partials over own key-half ----------------
  float zacc[16];
#pragma unroll
  for (int r = 0; r < 16; ++r) zacc[r] = 0.f;

  short8 st0, st1;
  {
    const unsigned short* s8 = kbase + (size_t)(th * 512 + sr) * DQ + so;
    st0 = *(const short8*)s8;
    st1 = *(const short8*)(s8 + 8);
  }
#pragma unroll 2
  for (int r = 0; r < 8; ++r) {
    const int buf = r & 1;
    *(short8*)&Ks[buf][th][sr][so] = st0;
    *(short8*)&Ks[buf][th][sr][so + 8] = st1;
    __syncthreads();
    if (r + 1 < 8) {
      const unsigned short* s8 =
          kbase + (size_t)(th * 512 + (r + 1) * 64 + sr) * DQ + so;
      st0 = *(const short8*)s8;
      st1 = *(const short8*)(s8 + 8);
    }
#pragma unroll
    for (int g = 0; g < 2; ++g) {
      f32x16 s = {0.f, 0.f, 0.f, 0.f, 0.f, 0.f, 0.f, 0.f,
                  0.f, 0.f, 0.f, 0.f, 0.f, 0.f, 0.f, 0.f};
#pragma unroll
      for (int ks = 0; ks < 4; ++ks) {
        short8 kb =
            *(const short8*)&Ks[buf][h][g * 32 + kcol][ks * 16 + lh * 8];
        s = __builtin_amdgcn_mfma_f32_32x32x16_bf16(qA[ks], kb, s, 0, 0, 0);
      }
#pragma unroll
      for (int reg = 0; reg < 16; ++reg)
        zacc[reg] += __builtin_amdgcn_exp2f(s[reg]);
    }
  }
  // butterfly over 32 key-cols (within lane-half); publish Z partial
#pragma unroll
  for (int reg = 0; reg < 16; ++reg) {
    float z = zacc[reg];
#pragma unroll
    for (int off = 1; off <= 16; off <<= 1) z += __shfl_xor(z, off, 64);
    const int row = rs * 32 + (reg & 3) + 8 * (reg >> 2) + 4 * lh;
    if (kcol == reg) zp[h * 128 + row] = z;
  }
  __syncthreads();
  float invz[16];
#pragma unroll
  for (int reg = 0; reg < 16; ++reg) {
    const int row = rs * 32 + (reg & 3) + 8 * (reg >> 2) + 4 * lh;
    invz[reg] = __builtin_amdgcn_rcpf(zp[row] + zp[128 + row]);
  }

  // ---------------- PASS 2: colsums over own key-half ----------------
  {
    const unsigned short* s8 = kbase + (size_t)(th * 512 + sr) * DQ + so;
    st0 = *(const short8*)s8;
    st1 = *(const short8*)(s8 + 8);
  }
#pragma unroll 2
  for (int r = 0; r < 8; ++r) {
    const int buf = r & 1;
    *(short8*)&Ks[buf][th][sr][so] = st0;
    *(short8*)&Ks[buf][th][sr][so + 8] = st1;
    __syncthreads();
    if (r + 1 < 8) {
      const unsigned short* s8 =
          kbase + (size_t)(th * 512 + (r + 1) * 64 + sr) * DQ + so;
      st0 = *(const short8*)s8;
      st1 = *(const short8*)(s8 + 8);
    }
#pragma unroll
    for (int g = 0; g < 2; ++g) {
      f32x16 s = {0.f, 0.f, 0.f, 0.f, 0.f, 0.f, 0.f, 0.f,
                  0.f, 0.f, 0.f, 0.f, 0.f, 0.f, 0.f, 0.f};
#pragma unroll
      for (int ks = 0; ks < 4; ++ks) {
        short8 kb =
            *(const short8*)&Ks[buf][h][g * 32 + kcol][ks * 16 + lh * 8];
        s = __builtin_amdgcn_mfma_f32_32x32x16_bf16(qA[ks], kb, s, 0, 0, 0);
      }
      float p = 0.f;
#pragma unroll
      for (int reg = 0; reg < 16; ++reg)
        p = fmaf(__builtin_amdgcn_exp2f(s[reg]), invz[reg], p);
      p += __shfl_xor(p, 32, 64);   // add the other 16 rows (other lane-half)
      if (lh == 0) cs[wave][r * 64 + g * 32 + kcol] = p;  // key local idx
    }
  }
  __syncthreads();
  // aw[k] = sum over rowsets; keys k<512 from h=0 waves (0,2,4,6), else odd
  for (int m = tid; m < 1024; m += 512) {
    const int hh = m >> 9, km = m & 511;
    const float a = cs[hh][km] + cs[2 + hh][km] + cs[4 + hh][km] + cs[6 + hh][km];
    cs[hh][km] = a;   // same thread read+write; aw lives in cs[0..1]
  }
  __syncthreads();

  // V-combine: partial O[d] over ALL 1024 keys
  const int d = tid & 63, g8 = tid >> 6;   // 8 groups x 128 keys
  {
    const int hh = g8 >> 2, base = (g8 & 3) * 128;
    const unsigned short* vb = &Vb[((size_t)bh * L_SEQ + g8 * 128) * DQ + d];
    float oacc = 0.f;
#pragma unroll 8
    for (int mm = 0; mm < 128; ++mm) {
      __hip_bfloat16 v;
      *(unsigned short*)&v = vb[(size_t)mm * DQ];
      oacc = fmaf(cs[hh][base + mm], __bfloat162float(v), oacc);
    }
    red[g8][d] = oacc;
  }
  __syncthreads();
  if (tid < 64) {
    float p = red[0][tid] + red[1][tid] + red[2][tid] + red[3][tid] +
              red[4][tid] + red[5][tid] + red[6][tid] + red[7][tid];
    atomicAdd(&Oacc[(size_t)bh * 64 + tid], p);
  }
  if (tid == 0) {
    __threadfence();                      // release
    lastFlag = (atomicAdd(&cnt[bh], 1) == 7);
  }
  __syncthreads();
  if (lastFlag && tid < 64) {
    __threadfence();                      // acquire
    float v = atomicAdd(&Oacc[(size_t)bh * 64 + tid], 0.f);
    float s = v;
#pragma unroll
    for (int off = 32; off >= 1; off >>= 1) s += __shfl_xor(s, off, 64);
    float mean = s * (1.f / 64.f);
    float diff = v - mean;
    float sq = diff * diff;
#pragma unroll
    for (int off = 32; off >= 1; off >>= 1) sq += __shfl_xor(sq, off, 64);
    float var = sq * (1.f / 64.f);
    float o = diff * rsqrtf(var + 1e-5f);
    const int b = bh >> 3, hh2 = bh & 7;
    out[(size_t)b * 512 + hh2 * 64 + tid] = o * gnw[hh2] + gnb[hh2];
  }
}

extern "C" void kernel_launch(void* const* d_in, const int* in_sizes, int n_in,
                              void* d_out, int out_size, void* d_ws,
                              size_t ws_size, hipStream_t stream) {
  (void)in_sizes; (void)n_in; (void)out_size; (void)ws_size;
  const float* emb  = (const float*)d_in[0];
  const float* W    = (const float*)d_in[1];
  const float* bias = (const float*)d_in[2];
  const float* gnw  = (const float*)d_in[3];
  const float* gnb  = (const float*)d_in[4];
  float* out = (float*)d_out;

  char* ws = (char*)d_ws;
  const size_t perQ = (size_t)BH * L_SEQ * DQ;        // 4,194,304 elems
  unsigned short* Qb = (unsigned short*)ws;           // 8 MB
  unsigned short* Kb = Qb + perQ;                     // 8 MB
  unsigned short* Vb = Kb + perQ;                     // 8 MB
  float* Oacc = (float*)(ws + 32u * 1024 * 1024);     // 16 KB
  int*   cnt  = (int*)(ws + 32u * 1024 * 1024 + 64u * 1024);

  qkv_mfma<<<dim3(768), 256, 0, stream>>>(
      emb, W, bias, Qb, Kb, Vb, Oacc, cnt);
  attn_fused<<<dim3(512), 512, 0, stream>>>(Qb, Kb, Vb, gnw, gnb,
                                            Oacc, cnt, out);
}